// Round 8
// baseline (106.024 us; speedup 1.0000x reference)
//
#include <hip/hip_runtime.h>

// DigitCaps on MI355X, fp32 I/O. R18 = R9 votes math + coalesced LDS staging
// of x and W (inner loop VMEM-free) + R17 two-stage reduce (verbatim).
// (R18 resubmit: previous round died on GPUAcquisitionTimeout, no data.)
// Session evidence:
//   R2: fp32 atomicAdd = CAS loop -> native int atomics only.
//   R3: seg sums winner-biased -> int64 on multi-block sums.
//   R5/R7/R8: VGPR cap below natural demand -> scratch spill.
//   R9: register W-slice, replicated LDS atomics -> 99.4us baseline.
//   R10 (deeper prefetch) neutral, R11 regression, R13 (dc->SGPR) neutral --
//     80 dc floats CANNOT fit the ~102-SGPR budget; R13 necessarily kept dc
//     in VGPRs (explains neutrality). dc stays plain VGPR (R9 form).
//   R14/R15: final fused INTO votes collapses codegen (VGPR=64, spill).
//   R16: bulk device-atomic combine serializes memory-side (+7us).
//   R17: two-stage reduce, 101.4 (noise band 99-101 across 6 designs).
//   Accounting (from R15's spilled votes=120/total=171): fixed floor ~51us
//     (fill 44 + restore ~7 + gaps); votes+reduce ~45-49us vs ~15 composed
//     floor. NEVER-ATTACKED stall: x inner-loop loads are 16-transaction
//     scatters (lane addrs span 16 rows x 147KB); W block-load is a cold
//     16-instr scatter. R18 coalesce-stages both into LDS (seq float4
//     bursts), inner loop reads x from LDS (stride-68 rows: 2-way = free).
//
// Sizes: B=128, J=4608, INPUT_D=8, D=8, M=4 -> N=18432 votes, C=10.
// Output = concat(output[128,10], digit_caps_new[10,8]).
// Math: output[b,c] = <(1/N) sum_n u[b,n], dc_new[c]> -> only s[b,:] needed.
//
// ws layout (BYTES):
//   [0,4)               done ticket counter (zeroed by votes block 0)
//   [64,24640)          part2_seg ll[32][96]  (col c*9+d; d==8 -> count)
//   [24640,155712)      part2_s  int[32][1024] (col h*512 + local_b*8+d)
//   [155712,598080)     part_seg int[1152][96]
//   [598080,2957376)    part_s   int[1152][512]

#define J_POS 4608
#define SEGSTRIDE 97        // 97%32=1 -> replica r occupies bank r%32
#define NSEG 32
#define SSTRIDE 520
#define NSREP 8
#define XSTRIDE 68          // x_lds row stride (floats): bank spread, 2-way max
#define NVOTES 18432.0f
#define DENOM  2359296.0f   // B*N
#define SEG_SCALE 32768.0f  // 2^15
#define INV_SEG_SCALE 3.0517578125e-5f
#define P2 32
#define ROWS_PER 36         // 32*36 = 1152

__global__ __launch_bounds__(256) void votes_kernel(
    const float* __restrict__ x,   // [B, J, 8]
    const float* __restrict__ w,   // [J, 8, 32]
    const float* __restrict__ dc,  // [10, 8]
    int* __restrict__ part_seg,
    int* __restrict__ part_s,
    int* __restrict__ done)
{
    __shared__ int   seg_lds[NSEG * SEGSTRIDE];  // 12.4 KB
    __shared__ int   s_lds[NSREP * SSTRIDE];     // 16.6 KB
    __shared__ float x_lds[64 * XSTRIDE];        // 17.4 KB (64 b-rows x 64f, pad 4)
    __shared__ float w_lds[2048];                // 8 KB (8 j x 256)

    const int t  = threadIdx.x;
    const int jg = blockIdx.x >> 1;
    const int h  = blockIdx.x & 1;      // batch half
    const int j0 = jg * 8;

    if (blockIdx.x == 0 && t == 0) *done = 0;   // reduce launches after us (stream order)

    for (int i = t; i < NSEG * SEGSTRIDE; i += 256) seg_lds[i] = 0;
    for (int i = t; i < NSREP * SSTRIDE; i += 256) s_lds[i] = 0;

    // ---- coalesced staging: W block (contiguous 2048 floats) -> LDS
    {
        const float* wsrc = w + (size_t)j0 * 256;
        #pragma unroll
        for (int rep = 0; rep < 2; ++rep) {
            const int f4 = rep * 256 + t;           // 0..511
            *(float4*)&w_lds[f4 * 4] = *(const float4*)(wsrc + f4 * 4);
        }
    }
    // ---- coalesced staging: x block (64 rows x 64 contiguous floats) -> LDS
    {
        #pragma unroll
        for (int rep = 0; rep < 4; ++rep) {
            const int idx = rep * 256 + t;          // 0..1023
            const int row = idx >> 4, f4 = idx & 15;
            *(float4*)&x_lds[row * XSTRIDE + f4 * 4] =
                *(const float4*)(x + ((size_t)(h * 64 + row) * J_POS + j0) * 8 + f4 * 4);
        }
    }

    const int jj   = t >> 5;           // 0..7 : this thread's j
    const int m    = (t >> 3) & 3;     // 0..3 : this thread's vote column
    const int brow = t & 7;            // 0..7 : batch row within iter

    // ---- all of dc -> 80 VGPRs (R9 form; 80 floats exceed the SGPR budget)
    float4 dca[10], dcb[10];
    #pragma unroll
    for (int c = 0; c < 10; ++c) {
        dca[c] = *(const float4*)(dc + c * 8);
        dcb[c] = *(const float4*)(dc + c * 8 + 4);
    }

    int* const segp = &seg_lds[((t >> 1) & (NSEG - 1)) * SEGSTRIDE];
    // lanes sharing one b in a wave = {jj&1, m} -> 8 distinct replicas: 1-way
    int* const sp = &s_lds[((t >> 3) & (NSREP - 1)) * SSTRIDE];

    __syncthreads();

    // ---- W slice regs from LDS (broadcast-friendly: 8 lanes share addr)
    float4 wra[8], wrb[8];
    {
        const float* wp = &w_lds[jj * 256 + m * 8];
        #pragma unroll
        for (int i = 0; i < 8; ++i) {
            wra[i] = *(const float4*)(wp + i * 32);
            wrb[i] = *(const float4*)(wp + i * 32 + 4);
        }
    }

    #pragma unroll 1
    for (int it = 0; it < 8; ++it) {
        const int bl = it * 8 + brow;       // local b 0..63
        // x from LDS: banks (bl*68 + jj*8)%32 -> brow spreads 4-apart,
        // jj overlap is 2-way (free, m136); m lanes broadcast.
        const float4 x0 = *(const float4*)&x_lds[bl * XSTRIDE + jj * 8];
        const float4 x1 = *(const float4*)&x_lds[bl * XSTRIDE + jj * 8 + 4];
        const float xf[8] = {x0.x,x0.y,x0.z,x0.w,x1.x,x1.y,x1.z,x1.w};

        // ---- one vote: u[8], all operands in registers
        float u[8] = {0,0,0,0,0,0,0,0};
        #pragma unroll
        for (int i = 0; i < 8; ++i) {
            const float xi = xf[i];
            u[0] += xi * wra[i].x; u[1] += xi * wra[i].y;
            u[2] += xi * wra[i].z; u[3] += xi * wra[i].w;
            u[4] += xi * wrb[i].x; u[5] += xi * wrb[i].y;
            u[6] += xi * wrb[i].z; u[7] += xi * wrb[i].w;
        }

        // ---- argmax over 10 caps (strict > = first max, jnp)
        float best = -3.402823466e38f;
        int bc = 0;
        #pragma unroll
        for (int c = 0; c < 10; ++c) {
            const float sim = u[0]*dca[c].x + u[1]*dca[c].y + u[2]*dca[c].z + u[3]*dca[c].w
                            + u[4]*dcb[c].x + u[5]*dcb[c].y + u[6]*dcb[c].z + u[7]*dcb[c].w;
            if (sim > best) { best = sim; bc = c; }
        }

        // ---- fixed-point LDS atomics, fire-and-forget
        const int o = bc * 9;
        const int sb = bl * 8;
        #pragma unroll
        for (int d = 0; d < 8; ++d) {
            const int q = __float2int_rn(u[d] * SEG_SCALE);
            atomicAdd(&segp[o + d], q);
            atomicAdd(&sp[sb + d], q);
        }
        atomicAdd(&segp[o + 8], 1);
    }

    __syncthreads();

    // ---- flush partials: plain coalesced stores, zero global atomics
    if (t < 90) {
        int v = 0;
        #pragma unroll
        for (int r = 0; r < NSEG; ++r) v += seg_lds[r * SEGSTRIDE + t];
        part_seg[blockIdx.x * 96 + t] = v;
    }
    #pragma unroll
    for (int e = t; e < 512; e += 256) {
        int v = 0;
        #pragma unroll
        for (int r = 0; r < NSREP; ++r) v += s_lds[r * SSTRIDE + e];
        part_s[(size_t)blockIdx.x * 512 + e] = v;
    }
}

// 32 blocks. Stage A: each reduces 36 rows -> part2 (agent stores).
// Ticket; last block runs stage B (32-row chains, L3-resident) + final.
__global__ __launch_bounds__(256) void reduce_final_kernel(
    const int* __restrict__ part_seg,
    const int* __restrict__ part_s,
    int* __restrict__ part2_s,         // [32][1024]
    long long* __restrict__ part2_seg, // [32][96]
    int* __restrict__ done,
    const float* __restrict__ dc,
    float* __restrict__ out)           // [0,1280): output  [1280,1360): dc_new
{
    __shared__ float sf[1024];
    __shared__ float dcn[80];
    __shared__ int lastflag;

    const int t = threadIdx.x;
    const int p = blockIdx.x;
    const int r0 = p * ROWS_PER;       // even, so row parity == (i&1)

    // ---- stage A, s: cols (2t, 2t+1) via int2, 36 rows, parity-split.
    int aE0 = 0, aE1 = 0, aO0 = 0, aO1 = 0;
    #pragma unroll
    for (int i = 0; i < ROWS_PER; ++i) {
        const int2 v = *(const int2*)(part_s + (size_t)(r0 + i) * 512 + 2 * t);
        if (i & 1) { aO0 += v.x; aO1 += v.y; }
        else       { aE0 += v.x; aE1 += v.y; }
    }
    __hip_atomic_store(&part2_s[p * 1024 + 2 * t],       aE0, __ATOMIC_RELAXED, __HIP_MEMORY_SCOPE_AGENT);
    __hip_atomic_store(&part2_s[p * 1024 + 2 * t + 1],   aE1, __ATOMIC_RELAXED, __HIP_MEMORY_SCOPE_AGENT);
    __hip_atomic_store(&part2_s[p * 1024 + 512 + 2 * t],     aO0, __ATOMIC_RELAXED, __HIP_MEMORY_SCOPE_AGENT);
    __hip_atomic_store(&part2_s[p * 1024 + 512 + 2 * t + 1], aO1, __ATOMIC_RELAXED, __HIP_MEMORY_SCOPE_AGENT);

    // ---- stage A, seg: col t (t<96), int64 acc (36-row winner-biased sums
    // can exceed int32 -- R3 lesson).
    if (t < 96) {
        long long acc = 0;
        #pragma unroll
        for (int i = 0; i < ROWS_PER; ++i)
            acc += part_seg[(size_t)(r0 + i) * 96 + t];
        __hip_atomic_store(&part2_seg[p * 96 + t], acc,
                           __ATOMIC_RELAXED, __HIP_MEMORY_SCOPE_AGENT);
    }

    // ---- ticket protocol (R13-proven): release, count, last finalizes.
    __threadfence();
    __syncthreads();
    if (t == 0) lastflag = (atomicAdd(done, 1) == P2 - 1) ? 1 : 0;
    __syncthreads();
    if (!lastflag) return;
    __threadfence();   // acquire side

    // ---- stage B, s totals: 4 cols/thread x 32 rows; int32 exact.
    // Same float op order as R13 -> bit-identical.
    #pragma unroll
    for (int g = 0; g < 2; ++g) {
        const int c0 = g * 512 + 2 * t;
        int t0 = 0, t1 = 0;
        #pragma unroll
        for (int q = 0; q < P2; ++q) {
            t0 += __hip_atomic_load(&part2_s[q * 1024 + c0],     __ATOMIC_RELAXED, __HIP_MEMORY_SCOPE_AGENT);
            t1 += __hip_atomic_load(&part2_s[q * 1024 + c0 + 1], __ATOMIC_RELAXED, __HIP_MEMORY_SCOPE_AGENT);
        }
        sf[c0]     = ((float)t0 * INV_SEG_SCALE) * (1.0f / NVOTES);
        sf[c0 + 1] = ((float)t1 * INV_SEG_SCALE) * (1.0f / NVOTES);
    }

    // ---- stage B, seg: (c,d) per thread, 32-row ll chains.
    if (t < 80) {
        const int c = t >> 3, d = t & 7;
        long long sv = 0, cv = 0;
        #pragma unroll
        for (int q = 0; q < P2; ++q) {
            sv += __hip_atomic_load(&part2_seg[q * 96 + c * 9 + d], __ATOMIC_RELAXED, __HIP_MEMORY_SCOPE_AGENT);
            cv += __hip_atomic_load(&part2_seg[q * 96 + c * 9 + 8], __ATOMIC_RELAXED, __HIP_MEMORY_SCOPE_AGENT);
        }
        const float d0 = dc[t];
        const float nd = d0 + ((float)sv * INV_SEG_SCALE - (float)cv * d0) * (1.0f / DENOM);
        dcn[t] = nd;
        out[1280 + t] = nd;
    }
    __syncthreads();

    #pragma unroll
    for (int r = 0; r < 5; ++r) {
        const int idx = r * 256 + t;        // 0..1279
        const int b = idx / 10, c = idx - b * 10;
        float acc = 0.f;
        #pragma unroll
        for (int d = 0; d < 8; ++d) acc += sf[b * 8 + d] * dcn[c * 8 + d];
        out[idx] = acc;
    }
}

extern "C" void kernel_launch(void* const* d_in, const int* in_sizes, int n_in,
                              void* d_out, int out_size, void* d_ws, size_t ws_size,
                              hipStream_t stream) {
    const float* x  = (const float*)d_in[0];
    const float* w  = (const float*)d_in[1];
    const float* dc = (const float*)d_in[2];
    float* out = (float*)d_out;
    int*       done      = (int*)d_ws;
    long long* part2_seg = (long long*)((char*)d_ws + 64);
    int*       part2_s   = (int*)((char*)d_ws + 24640);
    int*       part_seg  = (int*)((char*)d_ws + 155712);
    int*       part_s    = (int*)((char*)d_ws + 598080);

    votes_kernel<<<1152, 256, 0, stream>>>(x, w, dc, part_seg, part_s, done);
    reduce_final_kernel<<<P2, 256, 0, stream>>>(part_seg, part_s, part2_s,
                                                part2_seg, done, dc, out);
}

// Round 9
// 99.907 us; speedup vs baseline: 1.0612x; 1.0612x over previous
//
#include <hip/hip_runtime.h>

// DigitCaps on MI355X, fp32 I/O. R19 == exact revert to R9/R12 (champion:
// 99.2us measured twice). Final configuration after 8 structural probes.
// Session evidence:
//   R2: fp32 atomicAdd = CAS loop -> native int LDS atomics only.
//   R3: seg sums winner-biased -> int64/exact finals.
//   R5/R7/R8/R14/R15: ANY VGPR cap below natural ~216 demand -> scratch
//     spill (WRITE_SIZE detector); fusing final INTO votes collapses
//     codegen to VGPR=64 even uncapped. votes body is structurally pinned.
//   R9: register-resident W-slice + dc, one vote/thread/iter, replicated
//     fixed-point LDS atomics, plain-store flush -> 99.4/99.2us.
//   R10 (prefetch depth) neutral. R11 (fat blocks + DPP) -9%.
//   R13 (dc->SGPR) neutral: 80 dc floats exceed ~102-SGPR budget.
//   R16 (device-atomic combine) -8%: atomics serialize memory-side.
//   R17 (2-stage reduce) neutral. R18 (LDS-staged x/W) -7%: staging costs
//     more than the scatter it removes; VMEM latency already hidden.
//   Floor accounting: harness 256MiB d_ws re-poison fill = 43.5us @78%
//     HBM peak + d_in restore + dispatch gaps + reduce ~= 65-70us fixed;
//     votes ~20-25us sits ~2.5x its VALU floor on occupancy-latency that
//     requires VGPR<128 to fix -- impossible with W(64)+dc(80) resident,
//     and all eviction paths (SGPR/LDS/cap) tested or costed negative.
//
// Sizes: B=128, J=4608, INPUT_D=8, D=8, M=4 -> N=18432 votes, C=10.
// Output = concat(output[128,10], digit_caps_new[10,8]).
// Math: output[b,c] = <(1/N) sum_n u[b,n], dc_new[c]> -> only s[b,:] needed.
//
// ws layout (4B units):
//   [0]                 done counter
//   [64, 110656)        part_seg int [1152][96] (col c*9+d; d==8 -> count)
//   [110656, 700480)    part_s int [1152][512] (col = local_b*8+d, scale 2^15)
//   [700480, 701504)    s_final float [1024]
//   ll units [350752, 351136)  seg_part long long [4][96]

#define J_POS 4608
#define SEGSTRIDE 97        // 97%32=1 -> replica r occupies bank r%32
#define NSEG 32
#define SSTRIDE 520
#define NSREP 8
#define NVOTES 18432.0f
#define DENOM  2359296.0f   // B*N
#define SEG_SCALE 32768.0f  // 2^15
#define INV_SEG_SCALE 3.0517578125e-5f
#define OFF_PART_SEG 64
#define OFF_PART_S   110656
#define OFF_S_FINAL  700480
#define OFF_SEG_PART_LL 350752

__global__ __launch_bounds__(256) void votes_kernel(
    const float* __restrict__ x,   // [B, J, 8]
    const float* __restrict__ w,   // [J, 8, 32]
    const float* __restrict__ dc,  // [10, 8]
    int* __restrict__ part_seg,
    int* __restrict__ part_s,
    int* __restrict__ done)
{
    __shared__ int seg_lds[NSEG * SEGSTRIDE];   // 12.4 KB
    __shared__ int s_lds[NSREP * SSTRIDE];      // 16.6 KB

    const int t  = threadIdx.x;
    const int jg = blockIdx.x >> 1;
    const int h  = blockIdx.x & 1;      // batch half
    const int j0 = jg * 8;

    if (blockIdx.x == 0 && t == 0) *done = 0;   // reduce launches after us (stream order)

    for (int i = t; i < NSEG * SEGSTRIDE; i += 256) seg_lds[i] = 0;
    for (int i = t; i < NSREP * SSTRIDE; i += 256) s_lds[i] = 0;

    const int jj   = t >> 5;           // 0..7 : this thread's j
    const int m    = (t >> 3) & 3;     // 0..3 : this thread's vote column
    const int brow = t & 7;            // 0..7 : batch row within iter
    const int j = j0 + jj;

    // ---- W slice (8 i x 8 d for this (j,m)) -> 64 registers, loaded once
    float4 wra[8], wrb[8];
    {
        const float* wp = w + (size_t)j * 256 + m * 8;
        #pragma unroll
        for (int i = 0; i < 8; ++i) {
            wra[i] = *(const float4*)(wp + i * 32);
            wrb[i] = *(const float4*)(wp + i * 32 + 4);
        }
    }
    // ---- all of dc -> 80 registers (global broadcast reads, L2-served)
    float4 dca[10], dcb[10];
    #pragma unroll
    for (int c = 0; c < 10; ++c) {
        dca[c] = *(const float4*)(dc + c * 8);
        dcb[c] = *(const float4*)(dc + c * 8 + 4);
    }

    int* const segp = &seg_lds[((t >> 1) & (NSEG - 1)) * SEGSTRIDE];
    // lanes sharing one b in a wave = {jj&1, m} -> 8 distinct replicas: 1-way
    int* const sp = &s_lds[((t >> 3) & (NSREP - 1)) * SSTRIDE];

    __syncthreads();

    // ---- software-pipelined x loads (1-ahead) to hide HBM latency
    const float* xp0 = x + ((size_t)(h * 64 + brow) * J_POS + j) * 8;
    float4 nx0 = *(const float4*)xp0;
    float4 nx1 = *(const float4*)(xp0 + 4);

    #pragma unroll 1
    for (int it = 0; it < 8; ++it) {
        const int bl = it * 8 + brow;       // local b 0..63
        const float4 x0 = nx0, x1 = nx1;
        if (it < 7) {
            const float* xp = x + ((size_t)(h * 64 + bl + 8) * J_POS + j) * 8;
            nx0 = *(const float4*)xp;
            nx1 = *(const float4*)(xp + 4);
        }
        const float xf[8] = {x0.x,x0.y,x0.z,x0.w,x1.x,x1.y,x1.z,x1.w};

        // ---- one vote: u[8], all operands in registers
        float u[8] = {0,0,0,0,0,0,0,0};
        #pragma unroll
        for (int i = 0; i < 8; ++i) {
            const float xi = xf[i];
            u[0] += xi * wra[i].x; u[1] += xi * wra[i].y;
            u[2] += xi * wra[i].z; u[3] += xi * wra[i].w;
            u[4] += xi * wrb[i].x; u[5] += xi * wrb[i].y;
            u[6] += xi * wrb[i].z; u[7] += xi * wrb[i].w;
        }

        // ---- argmax over 10 caps, dc in registers (strict > = first max, jnp)
        float best = -3.402823466e38f;
        int bc = 0;
        #pragma unroll
        for (int c = 0; c < 10; ++c) {
            const float sim = u[0]*dca[c].x + u[1]*dca[c].y + u[2]*dca[c].z + u[3]*dca[c].w
                            + u[4]*dcb[c].x + u[5]*dcb[c].y + u[6]*dcb[c].z + u[7]*dcb[c].w;
            if (sim > best) { best = sim; bc = c; }
        }

        // ---- fixed-point LDS atomics, fire-and-forget
        const int o = bc * 9;
        const int sb = bl * 8;
        #pragma unroll
        for (int d = 0; d < 8; ++d) {
            const int q = __float2int_rn(u[d] * SEG_SCALE);
            atomicAdd(&segp[o + d], q);
            atomicAdd(&sp[sb + d], q);
        }
        atomicAdd(&segp[o + 8], 1);
    }

    __syncthreads();

    // ---- flush partials: plain coalesced stores, zero global atomics
    if (t < 90) {
        int v = 0;
        #pragma unroll
        for (int r = 0; r < NSEG; ++r) v += seg_lds[r * SEGSTRIDE + t];
        part_seg[blockIdx.x * 96 + t] = v;
    }
    #pragma unroll
    for (int e = t; e < 512; e += 256) {
        int v = 0;
        #pragma unroll
        for (int r = 0; r < NSREP; ++r) v += s_lds[r * SSTRIDE + e];
        part_s[(size_t)blockIdx.x * 512 + e] = v;
    }
}

// 20 blocks: 0..15 s-columns, 16..19 seg-quarters; last-done block runs the final.
__global__ __launch_bounds__(256) void reduce_final_kernel(
    const int* __restrict__ part_seg,
    const int* __restrict__ part_s,
    float* __restrict__ s_final,
    long long* __restrict__ seg_part,
    int* __restrict__ done,
    const float* __restrict__ dc,
    float* __restrict__ out)       // [0,1280): output  [1280,1360): dc_new
{
    __shared__ long long red[64][5];
    __shared__ long long segred[2][96];
    __shared__ float dcn[80];
    __shared__ float sf[1024];
    __shared__ int lastflag;

    const int t = threadIdx.x;
    const int bid = blockIdx.x;

    if (bid < 16) {
        // ---- s column-reduce: 64 cols, 4 chunks of 144 rows (parity h)
        const int g0 = bid * 64;
        const int h = g0 >> 9;
        const int gl = t & 63, chunk = t >> 6;
        const int col = (g0 + gl) & 511;
        long long acc = 0;
        #pragma unroll 8
        for (int i = chunk * 144; i < chunk * 144 + 144; ++i)
            acc += part_s[(size_t)(2 * i + h) * 512 + col];
        red[gl][chunk] = acc;
        __syncthreads();
        if (t < 64) {
            const long long v = red[t][0] + red[t][1] + red[t][2] + red[t][3];
            __hip_atomic_store(&s_final[g0 + t], (float)v * INV_SEG_SCALE,
                               __ATOMIC_RELAXED, __HIP_MEMORY_SCOPE_AGENT);
        }
    } else {
        // ---- seg quarter-reduce: 288 rows, 96 cols, 2 row-chunks
        const int p = bid - 16;
        if (t < 192) {
            const int o = t % 96, rc = t / 96;
            long long acc = 0;
            const int r0 = p * 288 + rc * 144;
            #pragma unroll 8
            for (int i = r0; i < r0 + 144; ++i)
                acc += part_seg[(size_t)i * 96 + o];
            segred[rc][o] = acc;
        }
        __syncthreads();
        if (t < 96)
            __hip_atomic_store(&seg_part[p * 96 + t], segred[0][t] + segred[1][t],
                               __ATOMIC_RELAXED, __HIP_MEMORY_SCOPE_AGENT);
    }

    // ---- completion protocol: release stores, count blocks, last one finalizes
    __threadfence();
    __syncthreads();
    if (t == 0) lastflag = (atomicAdd(done, 1) == 19) ? 1 : 0;
    __syncthreads();
    if (!lastflag) return;
    __threadfence();

    // ---- final (one block): dc_new + output GEMV; agent-scope loads of partials
    #pragma unroll
    for (int r = 0; r < 4; ++r) {
        const int i = r * 256 + t;
        const float v = __hip_atomic_load(&s_final[i], __ATOMIC_RELAXED,
                                          __HIP_MEMORY_SCOPE_AGENT);
        sf[i] = v * (1.0f / NVOTES);
    }
    if (t < 80) {
        const int c = t >> 3, d = t & 7;
        long long sv = 0, cv = 0;
        #pragma unroll
        for (int p = 0; p < 4; ++p) {
            sv += __hip_atomic_load(&seg_part[p * 96 + c * 9 + d], __ATOMIC_RELAXED,
                                    __HIP_MEMORY_SCOPE_AGENT);
            cv += __hip_atomic_load(&seg_part[p * 96 + c * 9 + 8], __ATOMIC_RELAXED,
                                    __HIP_MEMORY_SCOPE_AGENT);
        }
        const float d0 = dc[t];
        const float nd = d0 + ((float)sv * INV_SEG_SCALE - (float)cv * d0) * (1.0f / DENOM);
        dcn[t] = nd;
        out[1280 + t] = nd;
    }
    __syncthreads();

    #pragma unroll
    for (int r = 0; r < 5; ++r) {
        const int idx = r * 256 + t;        // 0..1279
        const int b = idx / 10, c = idx - b * 10;
        float acc = 0.f;
        #pragma unroll
        for (int d = 0; d < 8; ++d) acc += sf[b * 8 + d] * dcn[c * 8 + d];
        out[idx] = acc;
    }
}

extern "C" void kernel_launch(void* const* d_in, const int* in_sizes, int n_in,
                              void* d_out, int out_size, void* d_ws, size_t ws_size,
                              hipStream_t stream) {
    const float* x  = (const float*)d_in[0];
    const float* w  = (const float*)d_in[1];
    const float* dc = (const float*)d_in[2];
    float* out = (float*)d_out;
    int*       done      = (int*)d_ws;
    int*       part_seg  = (int*)d_ws + OFF_PART_SEG;
    int*       part_s    = (int*)d_ws + OFF_PART_S;
    float*     s_final   = (float*)d_ws + OFF_S_FINAL;
    long long* seg_part  = (long long*)d_ws + OFF_SEG_PART_LL;

    votes_kernel<<<1152, 256, 0, stream>>>(x, w, dc, part_seg, part_s, done);
    reduce_final_kernel<<<20, 256, 0, stream>>>(part_seg, part_s, s_final,
                                                seg_part, done, dc, out);
}